// Round 9
// baseline (106.595 us; speedup 1.0000x reference)
//
#include <hip/hip_runtime.h>
#include <math.h>

#define B 512
#define N 256
#define E 1024
#define D 256
#define H 256
#define C 8
#define U 64

// ---------------------------------------------------------------------------
// Mask dtype sniffing: flag 0 = int32 words, 1 = byte-packed bool, 2 = float32
// ---------------------------------------------------------------------------
__device__ __forceinline__ float mask_val(const void* m, long i, int flag) {
    if (flag == 1) return ((const unsigned char*)m)[i] ? 1.f : 0.f;
    if (flag == 2) return (((const float*)m)[i] != 0.f) ? 1.f : 0.f;
    return ((const int*)m)[i] ? 1.f : 0.f;
}

// block-wide sum reduction (256 threads)
__device__ __forceinline__ float block_sum(float v, float* red) {
    int t = threadIdx.x;
    red[t] = v; __syncthreads();
    for (int s = 128; s > 0; s >>= 1) {
        if (t < s) red[t] += red[t + s];
        __syncthreads();
    }
    float r = red[0]; __syncthreads();
    return r;
}

// ---------------------------------------------------------------------------
// k_h: per-batch trunk, 2 rows/block, 512 threads, grid=256.
// Block 0 sniffs the mask dtype into *flag.
// ---------------------------------------------------------------------------
__global__ __launch_bounds__(512) void k_h(
    const float* __restrict__ feat,
    const float* __restrict__ Wc1, const float* __restrict__ bc1,
    const float* __restrict__ Wc2, const float* __restrict__ bc2,
    const float* __restrict__ Wn1, const float* __restrict__ bn1,
    const float* __restrict__ We1, const float* __restrict__ be1,
    const float* __restrict__ Wg,  const float* __restrict__ bg,
    const float* __restrict__ margin, const float* __restrict__ brisk,
    const unsigned int* __restrict__ amask_words,
    float* __restrict__ base_n, float* __restrict__ base_e,
    float* __restrict__ out_gate, int* __restrict__ flag)
{
    __shared__ __align__(16) float sF[2][256];
    __shared__ __align__(16) float sH[2][256];
    __shared__ float red[512];
    __shared__ int cls0, cls1;

    int t = threadIdx.x;
    int w = t >> 8;        // 0/1: row in P1/P2, matrix in P3
    int c = t & 255;
    int b0 = blockIdx.x * 2;
    int b = b0 + w;

    if (blockIdx.x == 0) {
        if (t == 0) { cls0 = 0; cls1 = 0; }
        __syncthreads();
        if (t < 256) {
            unsigned int wd = amask_words[t];
            if (wd != 0u && wd != 1u) {
                if (wd == 0x3f800000u) atomicOr(&cls1, 1);
                else                   atomicOr(&cls0, 1);
            }
        }
        __syncthreads();
        if (t == 0) *flag = cls0 ? 1 : (cls1 ? 2 : 0);
    }

    sF[w][c] = feat[(long)b * D + c];
    __syncthreads();

    // ---- P1: relu(feat @ Wc1 + bc1) -> sH ----
    {
        float acc[4] = {bc1[c], 0.f, 0.f, 0.f};
        const float* Wp = Wc1 + c;
        for (int d0 = 0; d0 < D; d0 += 16) {
            float wv[16];
            #pragma unroll
            for (int k = 0; k < 16; k++) wv[k] = Wp[(long)(d0 + k) * H];
            #pragma unroll
            for (int k = 0; k < 16; k++)
                acc[k & 3] = fmaf(sF[w][d0 + k], wv[k], acc[k & 3]);
        }
        sH[w][c] = fmaxf((acc[0] + acc[1]) + (acc[2] + acc[3]), 0.f);
    }
    __syncthreads();

    // ---- P2: h = relu(A @ Wc2 + bc2) -> sF ----
    {
        float acc[4] = {bc2[c], 0.f, 0.f, 0.f};
        const float* Wp = Wc2 + c;
        for (int d0 = 0; d0 < H; d0 += 16) {
            float wv[16];
            #pragma unroll
            for (int k = 0; k < 16; k++) wv[k] = Wp[(long)(d0 + k) * H];
            #pragma unroll
            for (int k = 0; k < 16; k++)
                acc[k & 3] = fmaf(sH[w][d0 + k], wv[k], acc[k & 3]);
        }
        float a = fmaxf((acc[0] + acc[1]) + (acc[2] + acc[3]), 0.f);
        __syncthreads();
        sF[w][c] = a;                 // sF now holds h for both rows
    }
    __syncthreads();

    // ---- gate per row ----
    red[t] = sF[w][c] * Wg[c];
    __syncthreads();
    for (int s = 128; s > 0; s >>= 1) {
        if (c < s) red[t] += red[t + s];
        __syncthreads();
    }
    if (c == 0) {
        float lg = 1.f / (1.f + expf(-(red[t] + bg[0])));
        out_gate[b] = ((margin[b] < 0.2f) || (brisk[b] > 0.6f) || (lg > 0.5f)) ? 1.f : 0.f;
    }

    // ---- P3: base_n / base_e (thread-half = matrix, both rows) ----
    {
        const float* W3  = w ? (We1 + c) : (Wn1 + c);
        float bias       = w ? be1[c]    : bn1[c];
        float* dst       = w ? base_e    : base_n;
        float aA[2] = {bias, 0.f};
        float aB[2] = {bias, 0.f};
        for (int d0 = 0; d0 < H; d0 += 16) {
            float wv[16];
            #pragma unroll
            for (int k = 0; k < 16; k++) wv[k] = W3[(long)(d0 + k) * H];
            #pragma unroll
            for (int k = 0; k < 16; k++) {
                aA[k & 1] = fmaf(sF[0][d0 + k], wv[k], aA[k & 1]);
                aB[k & 1] = fmaf(sF[1][d0 + k], wv[k], aB[k & 1]);
            }
        }
        dst[(long)b0 * H + c]       = aA[0] + aA[1];
        dst[(long)(b0 + 1) * H + c] = aB[0] + aB[1];
    }
}

// ---------------------------------------------------------------------------
// k_ne: 128 threads = 2 waves per block. __launch_bounds__(128,3): VGPR cap
// ~170 so the q=8 edge register file (f[8][9]+acc[8] ~ 110 VGPR) does NOT
// spill (R8: default bounds capped at 80 -> scratch traffic in the j-loop).
// Blocks [0,256): NODE, 2 rows/block (wave = row, 4 items/lane). Wave-local
//   shuffle finalization (centering, top-2+idx, margin, riskbase).
// Blocks [256,768): EDGE, 1 row/block (wave = half row, 8 items/lane).
//   q=8 makes each wave-j visit 96 FMAs per 3 uniform ds_read_b128 ->
//   VALU-bound, not LDS-issue-bound (the ~69us wall of R2/R5/R7).
// Edge coords staged at stride 12 floats (48B) -> float4-aligned gathers.
// ---------------------------------------------------------------------------
__global__ __launch_bounds__(128, 3) void k_ne(
    const float* __restrict__ cs, const float* __restrict__ coords,
    const float* __restrict__ unc, const int* __restrict__ actions,
    const void* __restrict__ amask,
    const float* __restrict__ Wn1, const float* __restrict__ Wn2,
    const float* __restrict__ bn2, const float* __restrict__ base_n,
    const float* __restrict__ es, const int* __restrict__ edges,
    const void* __restrict__ emask,
    const float* __restrict__ We1, const float* __restrict__ We2,
    const float* __restrict__ be2, const float* __restrict__ base_e,
    const float* __restrict__ gate, const int* __restrict__ flagp,
    float* __restrict__ out0, float* __restrict__ out1,
    float* __restrict__ out2, float* __restrict__ out3,
    float* __restrict__ riskbase)
{
    __shared__ __align__(16) float smem[3072 + 3072]; // pack + (sB | sC12)
    float* pack = smem;
    int t = threadIdx.x;
    int w = t >> 6, lane = t & 63;
    int flag = *flagp;

    if (blockIdx.x < 256) {
        // ================= NODE: 2 rows, wave = row, q=4 =================
        int b0 = blockIdx.x * 2;
        float* sB = smem + 3072;   // [2][256] bases

        #pragma unroll
        for (int s = 0; s < 2; s++) {
            int j = t + 128 * s;
            float* p = pack + j * 12;
            #pragma unroll
            for (int k = 0; k < 10; k++) p[k] = Wn1[(long)(H + k) * H + j];
            p[10] = Wn2[j];
            p[11] = 0.f;
            sB[j]       = base_n[(long)b0 * H + j];
            sB[256 + j] = base_n[(long)(b0 + 1) * H + j];
        }
        __syncthreads();

        int b = b0 + w;
        float g = gate[b];
        float b2v = bn2[0];

        float f8v[4], ug[4], amv[4], acc[4];
        float f0[4], f1[4], f2[4], f3[4], f4[4], f5[4], f6[4], f7[4];
        #pragma unroll
        for (int q = 0; q < 4; q++) {
            int n = q * 64 + lane;
            const float4* cp = (const float4*)(coords + ((long)b * N + n) * C);
            float4 c0 = cp[0], c1 = cp[1];
            f0[q] = c0.x; f1[q] = c0.y; f2[q] = c0.z; f3[q] = c0.w;
            f4[q] = c1.x; f5[q] = c1.y; f6[q] = c1.z; f7[q] = c1.w;
            f8v[q] = cs[(long)b * N + n];
            int a = actions[(long)b * N + n];
            a = min(max(a, 0), U - 1);
            ug[q] = unc[(long)b * U + a];
            amv[q] = mask_val(amask, (long)b * N + n, flag);
            acc[q] = b2v;
        }

        float raw[4];
        if (g != 0.f) {
            const float* sBw = sB + w * 256;
            #pragma unroll 4
            for (int j = 0; j < H; j++) {
                const float* pj = pack + j * 12;
                float4 wa = *(const float4*)(pj);
                float4 wb = *(const float4*)(pj + 4);
                float4 wc = *(const float4*)(pj + 8);
                float bse = sBw[j];
                #pragma unroll
                for (int q = 0; q < 4; q++) {
                    float zA = fmaf(f0[q], wa.x, bse);
                    zA = fmaf(f1[q], wa.y, zA);
                    zA = fmaf(f2[q], wa.z, zA);
                    zA = fmaf(f3[q], wa.w, zA);
                    float zB = f4[q] * wb.x;
                    zB = fmaf(f5[q], wb.y, zB);
                    zB = fmaf(f6[q], wb.z, zB);
                    zB = fmaf(f7[q], wb.w, zB);
                    zB = fmaf(f8v[q], wc.x, zB);
                    zB = fmaf(ug[q], wc.y, zB);
                    acc[q] = fmaf(fmaxf(zA + zB, 0.f), wc.z, acc[q]);
                }
            }
            #pragma unroll
            for (int q = 0; q < 4; q++)
                raw[q] = (f8v[q] + g * 0.1f * (acc[q] * amv[q])) * amv[q];
        } else {
            #pragma unroll
            for (int q = 0; q < 4; q++) raw[q] = f8v[q] * amv[q];
        }

        // ---- wave-level finalization (no barriers) ----
        float s = 0.f, cn = 0.f, su = 0.f;
        #pragma unroll
        for (int q = 0; q < 4; q++) {
            s += raw[q]; cn += amv[q]; su += ug[q] * amv[q];
        }
        #pragma unroll
        for (int m = 1; m < 64; m <<= 1) {
            s  += __shfl_xor(s, m);
            cn += __shfl_xor(cn, m);
            su += __shfl_xor(su, m);
        }
        float denom = fmaxf(cn, 1.f);
        float mu = s / denom;

        float rs[4], masked[4];
        #pragma unroll
        for (int q = 0; q < 4; q++) {
            rs[q] = (raw[q] - mu) * amv[q];
            out0[(long)b * N + q * 64 + lane] = rs[q];
            masked[q] = (amv[q] != 0.f) ? rs[q] : -1e9f;
        }

        float v1 = masked[0]; int i1 = lane; float v2 = -1e9f;
        #pragma unroll
        for (int q = 1; q < 4; q++) {
            float mv = masked[q]; int mi = q * 64 + lane;
            if (mv > v1) { v2 = v1; v1 = mv; i1 = mi; }
            else v2 = fmaxf(v2, mv);
        }
        #pragma unroll
        for (int m = 1; m < 64; m <<= 1) {
            float ov1 = __shfl_xor(v1, m);
            int   oi1 = __shfl_xor(i1, m);
            float ov2 = __shfl_xor(v2, m);
            bool ow = (ov1 > v1) || (ov1 == v1 && oi1 < i1);
            float lv  = ow ? v1 : ov1;
            float wv2 = ow ? ov2 : v2;
            if (ow) { v1 = ov1; i1 = oi1; }
            v2 = fmaxf(lv, wv2);
        }

        if (lane == 0) {
            float rmargin = v1 - v2;
            out1[b] = rmargin;
            out3[b] = (float)i1;
            float sig = 1.f / (1.f + expf(rmargin));   // sigmoid(-margin)
            riskbase[b] = sig + 0.1f * (su / denom);
        }
    } else {
        // ================= EDGE: 1 row, wave = half row, q=8 =============
        int b = blockIdx.x - 256;
        float g = gate[b];

        if (g == 0.f) {
            #pragma unroll
            for (int q = 0; q < 8; q++) {
                long idx = (long)b * E + t + 128 * q;
                float em = mask_val(emask, idx, flag);
                out2[idx] = es[idx] * em;
            }
            return;
        }

        float* sC = smem + 3072;   // [256][12] coords, 48B stride (aligned)

        {
            const float4* g4 = (const float4*)(coords + (long)b * N * C);
            float4 c0 = g4[4 * t + 0], c1 = g4[4 * t + 1];
            float4 c2 = g4[4 * t + 2], c3 = g4[4 * t + 3];
            float4* d0 = (float4*)(sC + (2 * t) * 12);
            d0[0] = c0; d0[1] = c1;
            float4* d1 = (float4*)(sC + (2 * t + 1) * 12);
            d1[0] = c2; d1[1] = c3;
        }
        // pack: [0..7]=We1 k0..7, [8]=We1 k8 (es w), [9]=We2,
        // [10]=base_e[b]+w9 (emf fold), [11]=pad
        #pragma unroll
        for (int sdx = 0; sdx < 2; sdx++) {
            int j = t + 128 * sdx;
            float* p = pack + j * 12;
            #pragma unroll
            for (int k = 0; k < 9; k++) p[k] = We1[(long)(H + k) * H + j];
            p[9] = We2[j];
            p[10] = base_e[(long)b * H + j] + We1[(long)(H + 9) * H + j];
            p[11] = 0.f;
        }
        float b2v = be2[0];
        __syncthreads();

        float f[8][9], acc[8];
        #pragma unroll
        for (int q = 0; q < 8; q++) {
            int e = w * 512 + q * 64 + lane;
            long idx = (long)b * E + e;
            int2 ev = ((const int2*)edges)[idx];
            int s0 = min(max(ev.x, 0), N - 1);
            int d0 = min(max(ev.y, 0), N - 1);
            const float4* cs4 = (const float4*)(sC + s0 * 12);
            const float4* cd4 = (const float4*)(sC + d0 * 12);
            float4 sa = cs4[0], sb = cs4[1];
            float4 da = cd4[0], db = cd4[1];
            f[q][0] = da.x - sa.x; f[q][1] = da.y - sa.y;
            f[q][2] = da.z - sa.z; f[q][3] = da.w - sa.w;
            f[q][4] = db.x - sb.x; f[q][5] = db.y - sb.y;
            f[q][6] = db.z - sb.z; f[q][7] = db.w - sb.w;
            f[q][8] = es[idx];
            acc[q] = b2v;
        }

        #pragma unroll 4
        for (int j = 0; j < H; j++) {
            const float* pj = pack + j * 12;
            float4 wa = *(const float4*)(pj);
            float4 wb = *(const float4*)(pj + 4);
            float4 wc = *(const float4*)(pj + 8);
            #pragma unroll
            for (int q = 0; q < 8; q++) {
                float zA = fmaf(f[q][0], wa.x, wc.z);   // base (+w9 fold)
                zA = fmaf(f[q][1], wa.y, zA);
                zA = fmaf(f[q][2], wa.z, zA);
                zA = fmaf(f[q][3], wa.w, zA);
                float zB = f[q][4] * wb.x;
                zB = fmaf(f[q][5], wb.y, zB);
                zB = fmaf(f[q][6], wb.z, zB);
                zB = fmaf(f[q][7], wb.w, zB);
                zB = fmaf(f[q][8], wc.x, zB);
                acc[q] = fmaf(fmaxf(zA + zB, 0.f), wc.y, acc[q]);
            }
        }

        #pragma unroll
        for (int q = 0; q < 8; q++) {
            long idx = (long)b * E + w * 512 + q * 64 + lane;
            float em = mask_val(emask, idx, flag);
            out2[idx] = (em != 0.f) ? (f[q][8] + g * 0.1f * acc[q]) : 0.f;
        }
    }
}

// ---------------------------------------------------------------------------
// k_fin: edge mean/var -> evar, then out4 = clip(riskbase + 0.2*evar, 0, 1).
// ---------------------------------------------------------------------------
__global__ __launch_bounds__(256) void k_fin(
    const void* __restrict__ emask, const int* __restrict__ flagp,
    const float* __restrict__ out2, const float* __restrict__ riskbase,
    float* __restrict__ out4)
{
    __shared__ float red[256];
    int t = threadIdx.x;
    int b = blockIdx.x;
    int flag = *flagp;

    float x[4], em[4];
    float S1 = 0.f, ce = 0.f;
    #pragma unroll
    for (int q = 0; q < 4; q++) {
        long idx = (long)b * E + t + 256 * q;
        x[q] = out2[idx];
        em[q] = mask_val(emask, idx, flag);
        S1 += x[q]; ce += em[q];
    }
    float S1t = block_sum(S1, red);
    float cet = block_sum(ce, red);
    float mean = S1t / fmaxf(cet, 1.f);
    float v = 0.f;
    #pragma unroll
    for (int q = 0; q < 4; q++) {
        float dd = x[q] - mean;
        v = fmaf(em[q] * dd, dd, v);
    }
    float vt = block_sum(v, red);
    if (t == 0) {
        float var = vt / fmaxf(cet, 1.f);
        float ev = (cet > 1.f) ? var : 0.f;
        float r = riskbase[b] + 0.2f * ev;
        out4[b] = fminf(fmaxf(r, 0.f), 1.f);
    }
}

// ---------------------------------------------------------------------------
extern "C" void kernel_launch(void* const* d_in, const int* in_sizes, int n_in,
                              void* d_out, int out_size, void* d_ws, size_t ws_size,
                              hipStream_t stream) {
    const float* feat   = (const float*)d_in[0];
    const float* cs     = (const float*)d_in[1];
    const float* marg   = (const float*)d_in[2];
    const float* brisk  = (const float*)d_in[3];
    const float* es     = (const float*)d_in[4];
    const float* coords = (const float*)d_in[5];
    const float* unc    = (const float*)d_in[6];
    const float* Wc1    = (const float*)d_in[7];
    const float* bc1    = (const float*)d_in[8];
    const float* Wc2    = (const float*)d_in[9];
    const float* bc2    = (const float*)d_in[10];
    const float* Wn1    = (const float*)d_in[11];
    const float* bn1    = (const float*)d_in[12];
    const float* Wn2    = (const float*)d_in[13];
    const float* bn2    = (const float*)d_in[14];
    const float* We1    = (const float*)d_in[15];
    const float* be1    = (const float*)d_in[16];
    const float* We2    = (const float*)d_in[17];
    const float* be2    = (const float*)d_in[18];
    const float* Wg     = (const float*)d_in[19];
    const float* bg     = (const float*)d_in[20];
    const void*  amask  = d_in[21];
    const void*  emask  = d_in[22];
    const int*   actions= (const int*)d_in[23];
    const int*   edges  = (const int*)d_in[24];

    float* out0 = (float*)d_out;           // refined_scores (B,N)
    float* out1 = out0 + (long)B * N;      // refined_margin (B,)
    float* out2 = out1 + B;                // refined_edge (B,E)
    float* out3 = out2 + (long)B * E;      // top_idx (B,) as float
    float* out4 = out3 + B;                // refined_risk (B,)
    float* out5 = out4 + B;                // refine_gate (B,)

    float* base_n   = (float*)d_ws;                  // B*H
    float* base_e   = base_n + (long)B * H;          // B*H
    float* riskbase = base_e + (long)B * H;          // B
    int*   flag     = (int*)(riskbase + B);

    k_h<<<B / 2, 512, 0, stream>>>(feat, Wc1, bc1, Wc2, bc2, Wn1, bn1, We1, be1,
                                   Wg, bg, marg, brisk,
                                   (const unsigned int*)amask,
                                   base_n, base_e, out5, flag);
    k_ne<<<256 + B, 128, 0, stream>>>(cs, coords, unc, actions, amask,
                                      Wn1, Wn2, bn2, base_n,
                                      es, edges, emask,
                                      We1, We2, be2, base_e,
                                      out5, flag,
                                      out0, out1, out2, out3, riskbase);
    k_fin<<<B, 256, 0, stream>>>(emask, flag, out2, riskbase, out4);
}

// Round 11
// 82.287 us; speedup vs baseline: 1.2954x; 1.2954x over previous
//
#include <hip/hip_runtime.h>
#include <math.h>

#define B 512
#define N 256
#define E 1024
#define D 256
#define H 256
#define C 8
#define U 64

typedef __fp16 h2 __attribute__((ext_vector_type(2)));
union UF { float f; h2 h; unsigned u; };

__device__ __forceinline__ float bc_f(h2 h) { UF u; u.h = h; return u.f; }
__device__ __forceinline__ h2 bc_h(float f) { UF u; u.f = f; return u.h; }

#if __has_builtin(__builtin_amdgcn_cvt_pkrtz)
__device__ __forceinline__ h2 pkh(float a, float b) { return __builtin_amdgcn_cvt_pkrtz(a, b); }
#else
__device__ __forceinline__ h2 pkh(float a, float b) { h2 r; r.x = (__fp16)a; r.y = (__fp16)b; return r; }
#endif

#if __has_builtin(__builtin_amdgcn_fdot2)
__device__ __forceinline__ float FDOT2(h2 a, h2 b, float c) { return __builtin_amdgcn_fdot2(a, b, c, false); }
#else
__device__ __forceinline__ float FDOT2(h2 a, h2 b, float c) {
    return fmaf((float)a.x, (float)b.x, fmaf((float)a.y, (float)b.y, c));
}
#endif

// ---------------------------------------------------------------------------
// Mask dtype sniffing: flag 0 = int32 words, 1 = byte-packed bool, 2 = float32
// ---------------------------------------------------------------------------
__device__ __forceinline__ float mask_val(const void* m, long i, int flag) {
    if (flag == 1) return ((const unsigned char*)m)[i] ? 1.f : 0.f;
    if (flag == 2) return (((const float*)m)[i] != 0.f) ? 1.f : 0.f;
    return ((const int*)m)[i] ? 1.f : 0.f;
}

// block-wide sum reduction (256 threads, red = 256 floats)
__device__ __forceinline__ float block_sum(float v, float* red) {
    int t = threadIdx.x;
    red[t] = v; __syncthreads();
    for (int s = 128; s > 0; s >>= 1) {
        if (t < s) red[t] += red[t + s];
        __syncthreads();
    }
    float r = red[0]; __syncthreads();
    return r;
}

// ---------------------------------------------------------------------------
// k_h: per-batch trunk, 4 rows/block, 512 threads, grid=128 (halves L2
// weight traffic vs 2-row version). Block 0 sniffs mask dtype.
// ---------------------------------------------------------------------------
__global__ __launch_bounds__(512) void k_h(
    const float* __restrict__ feat,
    const float* __restrict__ Wc1, const float* __restrict__ bc1,
    const float* __restrict__ Wc2, const float* __restrict__ bc2,
    const float* __restrict__ Wn1, const float* __restrict__ bn1,
    const float* __restrict__ We1, const float* __restrict__ be1,
    const float* __restrict__ Wg,  const float* __restrict__ bg,
    const float* __restrict__ margin, const float* __restrict__ brisk,
    const unsigned int* __restrict__ amask_words,
    float* __restrict__ base_n, float* __restrict__ base_e,
    float* __restrict__ out_gate, int* __restrict__ flag)
{
    __shared__ __align__(16) float sF[4][256];
    __shared__ __align__(16) float sH[4][256];
    __shared__ float red[512];
    __shared__ int cls0, cls1;

    int t = threadIdx.x;
    int w = t >> 8;        // 0/1
    int c = t & 255;
    int b0 = blockIdx.x * 4;
    int r0 = 2 * w, r1 = 2 * w + 1;

    if (blockIdx.x == 0) {
        if (t == 0) { cls0 = 0; cls1 = 0; }
        __syncthreads();
        if (t < 256) {
            unsigned int wd = amask_words[t];
            if (wd != 0u && wd != 1u) {
                if (wd == 0x3f800000u) atomicOr(&cls1, 1);
                else                   atomicOr(&cls0, 1);
            }
        }
        __syncthreads();
        if (t == 0) *flag = cls0 ? 1 : (cls1 ? 2 : 0);
    }

    sF[r0][c] = feat[(long)(b0 + r0) * D + c];
    sF[r1][c] = feat[(long)(b0 + r1) * D + c];
    __syncthreads();

    // ---- P1: relu(feat @ Wc1 + bc1) -> sH (2 rows per thread) ----
    {
        float aA[2] = {bc1[c], 0.f}, aB[2] = {bc1[c], 0.f};
        const float* Wp = Wc1 + c;
        for (int d0 = 0; d0 < D; d0 += 16) {
            float wv[16];
            #pragma unroll
            for (int k = 0; k < 16; k++) wv[k] = Wp[(long)(d0 + k) * H];
            #pragma unroll
            for (int k = 0; k < 16; k++) {
                aA[k & 1] = fmaf(sF[r0][d0 + k], wv[k], aA[k & 1]);
                aB[k & 1] = fmaf(sF[r1][d0 + k], wv[k], aB[k & 1]);
            }
        }
        sH[r0][c] = fmaxf(aA[0] + aA[1], 0.f);
        sH[r1][c] = fmaxf(aB[0] + aB[1], 0.f);
    }
    __syncthreads();

    // ---- P2: h = relu(A @ Wc2 + bc2) -> sF ----
    {
        float aA[2] = {bc2[c], 0.f}, aB[2] = {bc2[c], 0.f};
        const float* Wp = Wc2 + c;
        for (int d0 = 0; d0 < H; d0 += 16) {
            float wv[16];
            #pragma unroll
            for (int k = 0; k < 16; k++) wv[k] = Wp[(long)(d0 + k) * H];
            #pragma unroll
            for (int k = 0; k < 16; k++) {
                aA[k & 1] = fmaf(sH[r0][d0 + k], wv[k], aA[k & 1]);
                aB[k & 1] = fmaf(sH[r1][d0 + k], wv[k], aB[k & 1]);
            }
        }
        float hA = fmaxf(aA[0] + aA[1], 0.f);
        float hB = fmaxf(aB[0] + aB[1], 0.f);
        __syncthreads();
        sF[r0][c] = hA;
        sF[r1][c] = hB;
    }
    __syncthreads();

    // ---- gate per row (two rounds) ----
    #pragma unroll
    for (int rr = 0; rr < 2; rr++) {
        int r = 2 * w + rr;
        red[t] = sF[r][c] * Wg[c];
        __syncthreads();
        for (int s = 128; s > 0; s >>= 1) {
            if (c < s) red[t] += red[t + s];
            __syncthreads();
        }
        if (c == 0) {
            int b = b0 + r;
            float lg = 1.f / (1.f + expf(-(red[t] + bg[0])));
            out_gate[b] = ((margin[b] < 0.2f) || (brisk[b] > 0.6f) || (lg > 0.5f)) ? 1.f : 0.f;
        }
        __syncthreads();
    }

    // ---- P3: base_n / base_e (thread-half = matrix, all 4 rows) ----
    {
        const float* W3  = w ? (We1 + c) : (Wn1 + c);
        float bias       = w ? be1[c]    : bn1[c];
        float* dst       = w ? base_e    : base_n;
        float aA[2] = {bias, 0.f}, aB[2] = {bias, 0.f};
        float aC[2] = {bias, 0.f}, aD[2] = {bias, 0.f};
        for (int d0 = 0; d0 < H; d0 += 16) {
            float wv[16];
            #pragma unroll
            for (int k = 0; k < 16; k++) wv[k] = W3[(long)(d0 + k) * H];
            #pragma unroll
            for (int k = 0; k < 16; k++) {
                aA[k & 1] = fmaf(sF[0][d0 + k], wv[k], aA[k & 1]);
                aB[k & 1] = fmaf(sF[1][d0 + k], wv[k], aB[k & 1]);
                aC[k & 1] = fmaf(sF[2][d0 + k], wv[k], aC[k & 1]);
                aD[k & 1] = fmaf(sF[3][d0 + k], wv[k], aD[k & 1]);
            }
        }
        dst[(long)(b0 + 0) * H + c] = aA[0] + aA[1];
        dst[(long)(b0 + 1) * H + c] = aB[0] + aB[1];
        dst[(long)(b0 + 2) * H + c] = aC[0] + aC[1];
        dst[(long)(b0 + 3) * H + c] = aD[0] + aD[1];
    }
}

// ---------------------------------------------------------------------------
// k_ne: 256 threads = 4 waves.
// Blocks [0,128): NODE, 4 rows/block (wave = row, q=4, pure fp32).
// Blocks [128,640): EDGE, 1 row/block (wave = quarter row, q=4), f16-packed
//   weights+features with v_dot2_f32_f16 (f32 accum); mean/var fused.
// ---------------------------------------------------------------------------
__global__ __launch_bounds__(256, 2) void k_ne(
    const float* __restrict__ cs, const float* __restrict__ coords,
    const float* __restrict__ unc, const int* __restrict__ actions,
    const void* __restrict__ amask,
    const float* __restrict__ Wn1, const float* __restrict__ Wn2,
    const float* __restrict__ bn2, const float* __restrict__ base_n,
    const float* __restrict__ es, const int* __restrict__ edges,
    const void* __restrict__ emask,
    const float* __restrict__ We1, const float* __restrict__ We2,
    const float* __restrict__ be2, const float* __restrict__ base_e,
    const float* __restrict__ gate, const int* __restrict__ flagp,
    float* __restrict__ out0, float* __restrict__ out1,
    float* __restrict__ out2, float* __restrict__ out3,
    float* __restrict__ riskbase, float* __restrict__ evar)
{
    __shared__ __align__(16) float smem[4864];   // 19456 B
    int t = threadIdx.x;
    int w = t >> 6, lane = t & 63;
    int flag = *flagp;

    if (blockIdx.x < 128) {
        // ================= NODE: 4 rows, wave = row, q=4, fp32 ===========
        float* pack = smem;            // [256][12] f32
        float* sB   = smem + 3072;     // [4][256] bases
        int b0 = blockIdx.x * 4;

        {
            float* p = pack + t * 12;
            #pragma unroll
            for (int k = 0; k < 10; k++) p[k] = Wn1[(long)(H + k) * H + t];
            p[10] = Wn2[t];
            p[11] = 0.f;
            #pragma unroll
            for (int r = 0; r < 4; r++)
                sB[r * 256 + t] = base_n[(long)(b0 + r) * H + t];
        }
        __syncthreads();

        int b = b0 + w;
        float g = gate[b];
        float b2v = bn2[0];

        float f8v[4], ug[4], amv[4], acc[4];
        float f0[4], f1[4], f2[4], f3[4], f4[4], f5[4], f6[4], f7[4];
        #pragma unroll
        for (int q = 0; q < 4; q++) {
            int n = q * 64 + lane;
            const float4* cp = (const float4*)(coords + ((long)b * N + n) * C);
            float4 c0 = cp[0], c1 = cp[1];
            f0[q] = c0.x; f1[q] = c0.y; f2[q] = c0.z; f3[q] = c0.w;
            f4[q] = c1.x; f5[q] = c1.y; f6[q] = c1.z; f7[q] = c1.w;
            f8v[q] = cs[(long)b * N + n];
            int a = actions[(long)b * N + n];
            a = min(max(a, 0), U - 1);
            ug[q] = unc[(long)b * U + a];
            amv[q] = mask_val(amask, (long)b * N + n, flag);
            acc[q] = b2v;
        }

        float raw[4];
        if (g != 0.f) {
            const float* sBw = sB + w * 256;
            #pragma unroll 4
            for (int j = 0; j < H; j++) {
                const float* pj = pack + j * 12;
                float4 wa = *(const float4*)(pj);
                float4 wb = *(const float4*)(pj + 4);
                float4 wc = *(const float4*)(pj + 8);
                float bse = sBw[j];
                #pragma unroll
                for (int q = 0; q < 4; q++) {
                    float zA = fmaf(f0[q], wa.x, bse);
                    zA = fmaf(f1[q], wa.y, zA);
                    zA = fmaf(f2[q], wa.z, zA);
                    zA = fmaf(f3[q], wa.w, zA);
                    float zB = f4[q] * wb.x;
                    zB = fmaf(f5[q], wb.y, zB);
                    zB = fmaf(f6[q], wb.z, zB);
                    zB = fmaf(f7[q], wb.w, zB);
                    zB = fmaf(f8v[q], wc.x, zB);
                    zB = fmaf(ug[q], wc.y, zB);
                    acc[q] = fmaf(fmaxf(zA + zB, 0.f), wc.z, acc[q]);
                }
            }
            #pragma unroll
            for (int q = 0; q < 4; q++)
                raw[q] = (f8v[q] + g * 0.1f * (acc[q] * amv[q])) * amv[q];
        } else {
            #pragma unroll
            for (int q = 0; q < 4; q++) raw[q] = f8v[q] * amv[q];
        }

        // ---- wave-level finalization ----
        float s = 0.f, cn = 0.f, su = 0.f;
        #pragma unroll
        for (int q = 0; q < 4; q++) {
            s += raw[q]; cn += amv[q]; su += ug[q] * amv[q];
        }
        #pragma unroll
        for (int m = 1; m < 64; m <<= 1) {
            s  += __shfl_xor(s, m);
            cn += __shfl_xor(cn, m);
            su += __shfl_xor(su, m);
        }
        float denom = fmaxf(cn, 1.f);
        float mu = s / denom;

        float rs[4], masked[4];
        #pragma unroll
        for (int q = 0; q < 4; q++) {
            rs[q] = (raw[q] - mu) * amv[q];
            out0[(long)b * N + q * 64 + lane] = rs[q];
            masked[q] = (amv[q] != 0.f) ? rs[q] : -1e9f;
        }

        float v1 = masked[0]; int i1 = lane; float v2 = -1e9f;
        #pragma unroll
        for (int q = 1; q < 4; q++) {
            float mv = masked[q]; int mi = q * 64 + lane;
            if (mv > v1) { v2 = v1; v1 = mv; i1 = mi; }
            else v2 = fmaxf(v2, mv);
        }
        #pragma unroll
        for (int m = 1; m < 64; m <<= 1) {
            float ov1 = __shfl_xor(v1, m);
            int   oi1 = __shfl_xor(i1, m);
            float ov2 = __shfl_xor(v2, m);
            bool ow = (ov1 > v1) || (ov1 == v1 && oi1 < i1);
            float lv  = ow ? v1 : ov1;
            float wv2 = ow ? ov2 : v2;
            if (ow) { v1 = ov1; i1 = oi1; }
            v2 = fmaxf(lv, wv2);
        }

        if (lane == 0) {
            float rmargin = v1 - v2;
            out1[b] = rmargin;
            out3[b] = (float)i1;
            float sig = 1.f / (1.f + expf(rmargin));   // sigmoid(-margin)
            riskbase[b] = sig + 0.1f * (su / denom);
        }
    } else {
        // ================= EDGE: 1 row, wave = quarter, q=4, f16 =========
        float*  A4 = smem;             // [256] float4: w0..w7 as 4 half2
        float2* B2 = (float2*)(smem + 1024);  // [256] float2: (w8,We2)h2, base'
        float*  sC = smem + 1536;      // [256][12] f32 coords (stride 12)
        float*  red = smem + 4608;     // [256]
        int b = blockIdx.x - 128;
        float g = gate[b];

        float re[4], emv[4];
        if (g != 0.f) {
            // stage coords + f16 weight pack
            {
                const float4* g4 = (const float4*)(coords + (long)b * N * C);
                float4 c0 = g4[2 * t], c1 = g4[2 * t + 1];
                float4* d0 = (float4*)(sC + t * 12);
                d0[0] = c0; d0[1] = c1;

                float w0 = We1[(long)(H + 0) * H + t];
                float w1 = We1[(long)(H + 1) * H + t];
                float w2 = We1[(long)(H + 2) * H + t];
                float w3 = We1[(long)(H + 3) * H + t];
                float w4 = We1[(long)(H + 4) * H + t];
                float w5 = We1[(long)(H + 5) * H + t];
                float w6 = We1[(long)(H + 6) * H + t];
                float w7 = We1[(long)(H + 7) * H + t];
                float w8 = We1[(long)(H + 8) * H + t];
                float w9 = We1[(long)(H + 9) * H + t];
                float we2 = We2[t];
                float bse = base_e[(long)b * H + t] + w9;   // emf==1 fold
                float4 av;
                av.x = bc_f(pkh(w0, w1)); av.y = bc_f(pkh(w2, w3));
                av.z = bc_f(pkh(w4, w5)); av.w = bc_f(pkh(w6, w7));
                ((float4*)A4)[t] = av;
                B2[t] = make_float2(bc_f(pkh(w8, we2)), bse);
            }
            float b2v = be2[0];
            __syncthreads();

            // gather + diff + f16-pack features
            float p01[4], p23[4], p45[4], p67[4], pes[4], esv[4], acc[4];
            #pragma unroll
            for (int q = 0; q < 4; q++) {
                int e = w * 256 + q * 64 + lane;
                long idx = (long)b * E + e;
                int2 ev = ((const int2*)edges)[idx];
                int s0 = min(max(ev.x, 0), N - 1);
                int d0 = min(max(ev.y, 0), N - 1);
                const float4* cs4 = (const float4*)(sC + s0 * 12);
                const float4* cd4 = (const float4*)(sC + d0 * 12);
                float4 sa = cs4[0], sb = cs4[1];
                float4 da = cd4[0], db = cd4[1];
                p01[q] = bc_f(pkh(da.x - sa.x, da.y - sa.y));
                p23[q] = bc_f(pkh(da.z - sa.z, da.w - sa.w));
                p45[q] = bc_f(pkh(db.x - sb.x, db.y - sb.y));
                p67[q] = bc_f(pkh(db.z - sb.z, db.w - sb.w));
                esv[q] = es[idx];
                pes[q] = bc_f(pkh(esv[q], 0.f));
                emv[q] = mask_val(emask, idx, flag);
                acc[q] = b2v;
            }

            const float4* A4v = (const float4*)A4;
            #pragma unroll 2
            for (int j = 0; j < H; j++) {
                float4 av = A4v[j];
                float2 bv = B2[j];
                h2 w01 = bc_h(av.x), w23 = bc_h(av.y);
                h2 w45 = bc_h(av.z), w67 = bc_h(av.w);
                h2 w8x = bc_h(bv.x);
                float we2f = (float)(w8x.y);
                float bse = bv.y;
                #pragma unroll
                for (int q = 0; q < 4; q++) {
                    float z = FDOT2(bc_h(p01[q]), w01, bse);
                    z = FDOT2(bc_h(p23[q]), w23, z);
                    z = FDOT2(bc_h(p45[q]), w45, z);
                    z = FDOT2(bc_h(p67[q]), w67, z);
                    z = FDOT2(bc_h(pes[q]), w8x, z);
                    acc[q] = fmaf(fmaxf(z, 0.f), we2f, acc[q]);
                }
            }

            #pragma unroll
            for (int q = 0; q < 4; q++) {
                long idx = (long)b * E + w * 256 + q * 64 + lane;
                re[q] = (emv[q] != 0.f) ? (esv[q] + g * 0.1f * acc[q]) : 0.f;
                out2[idx] = re[q];
            }
            __syncthreads();   // pack/coord reads done before red reuse
        } else {
            #pragma unroll
            for (int q = 0; q < 4; q++) {
                long idx = (long)b * E + w * 256 + q * 64 + lane;
                emv[q] = mask_val(emask, idx, flag);
                re[q] = es[idx] * emv[q];
                out2[idx] = re[q];
            }
        }

        // ---- fused mean/var (values in registers) ----
        float S1 = 0.f, ce = 0.f;
        #pragma unroll
        for (int q = 0; q < 4; q++) { S1 += re[q]; ce += emv[q]; }
        float S1t = block_sum(S1, red);
        float cet = block_sum(ce, red);
        float mean = S1t / fmaxf(cet, 1.f);
        float v = 0.f;
        #pragma unroll
        for (int q = 0; q < 4; q++) {
            float dd = re[q] - mean;
            v = fmaf(emv[q] * dd, dd, v);
        }
        float vt = block_sum(v, red);
        if (t == 0) {
            float var = vt / fmaxf(cet, 1.f);
            evar[b] = (cet > 1.f) ? var : 0.f;
        }
    }
}

// ---------------------------------------------------------------------------
// k_risk: out4 = clip(riskbase + 0.2*evar, 0, 1)
// ---------------------------------------------------------------------------
__global__ __launch_bounds__(256) void k_risk(
    const float* __restrict__ riskbase, const float* __restrict__ evar,
    float* __restrict__ out4)
{
    int b = blockIdx.x * 256 + threadIdx.x;
    float r = riskbase[b] + 0.2f * evar[b];
    out4[b] = fminf(fmaxf(r, 0.f), 1.f);
}

// ---------------------------------------------------------------------------
extern "C" void kernel_launch(void* const* d_in, const int* in_sizes, int n_in,
                              void* d_out, int out_size, void* d_ws, size_t ws_size,
                              hipStream_t stream) {
    const float* feat   = (const float*)d_in[0];
    const float* cs     = (const float*)d_in[1];
    const float* marg   = (const float*)d_in[2];
    const float* brisk  = (const float*)d_in[3];
    const float* es     = (const float*)d_in[4];
    const float* coords = (const float*)d_in[5];
    const float* unc    = (const float*)d_in[6];
    const float* Wc1    = (const float*)d_in[7];
    const float* bc1    = (const float*)d_in[8];
    const float* Wc2    = (const float*)d_in[9];
    const float* bc2    = (const float*)d_in[10];
    const float* Wn1    = (const float*)d_in[11];
    const float* bn1    = (const float*)d_in[12];
    const float* Wn2    = (const float*)d_in[13];
    const float* bn2    = (const float*)d_in[14];
    const float* We1    = (const float*)d_in[15];
    const float* be1    = (const float*)d_in[16];
    const float* We2    = (const float*)d_in[17];
    const float* be2    = (const float*)d_in[18];
    const float* Wg     = (const float*)d_in[19];
    const float* bg     = (const float*)d_in[20];
    const void*  amask  = d_in[21];
    const void*  emask  = d_in[22];
    const int*   actions= (const int*)d_in[23];
    const int*   edges  = (const int*)d_in[24];

    float* out0 = (float*)d_out;           // refined_scores (B,N)
    float* out1 = out0 + (long)B * N;      // refined_margin (B,)
    float* out2 = out1 + B;                // refined_edge (B,E)
    float* out3 = out2 + (long)B * E;      // top_idx (B,) as float
    float* out4 = out3 + B;                // refined_risk (B,)
    float* out5 = out4 + B;                // refine_gate (B,)

    float* base_n   = (float*)d_ws;                  // B*H
    float* base_e   = base_n + (long)B * H;          // B*H
    float* riskbase = base_e + (long)B * H;          // B
    float* evar     = riskbase + B;                  // B
    int*   flag     = (int*)(evar + B);

    k_h<<<B / 4, 512, 0, stream>>>(feat, Wc1, bc1, Wc2, bc2, Wn1, bn1, We1, be1,
                                   Wg, bg, marg, brisk,
                                   (const unsigned int*)amask,
                                   base_n, base_e, out5, flag);
    k_ne<<<128 + B, 256, 0, stream>>>(cs, coords, unc, actions, amask,
                                      Wn1, Wn2, bn2, base_n,
                                      es, edges, emask,
                                      We1, We2, be2, base_e,
                                      out5, flag,
                                      out0, out1, out2, out3, riskbase, evar);
    k_risk<<<2, 256, 0, stream>>>(riskbase, evar, out4);
}

// Round 12
// 77.541 us; speedup vs baseline: 1.3747x; 1.0612x over previous
//
#include <hip/hip_runtime.h>
#include <math.h>

#define B 512
#define N 256
#define E 1024
#define D 256
#define H 256
#define C 8
#define U 64

typedef __fp16 h2 __attribute__((ext_vector_type(2)));
union UF { float f; h2 h; unsigned u; };

__device__ __forceinline__ float bc_f(h2 h) { UF u; u.h = h; return u.f; }
__device__ __forceinline__ h2 bc_h(float f) { UF u; u.f = f; return u.h; }

#if __has_builtin(__builtin_amdgcn_cvt_pkrtz)
__device__ __forceinline__ h2 pkh(float a, float b) { return __builtin_amdgcn_cvt_pkrtz(a, b); }
#else
__device__ __forceinline__ h2 pkh(float a, float b) { h2 r; r.x = (__fp16)a; r.y = (__fp16)b; return r; }
#endif

#if __has_builtin(__builtin_amdgcn_fdot2)
__device__ __forceinline__ float FDOT2(h2 a, h2 b, float c) { return __builtin_amdgcn_fdot2(a, b, c, false); }
#else
__device__ __forceinline__ float FDOT2(h2 a, h2 b, float c) {
    return fmaf((float)a.x, (float)b.x, fmaf((float)a.y, (float)b.y, c));
}
#endif

// ---------------------------------------------------------------------------
__device__ __forceinline__ float mask_val(const void* m, long i, int flag) {
    if (flag == 1) return ((const unsigned char*)m)[i] ? 1.f : 0.f;
    if (flag == 2) return (((const float*)m)[i] != 0.f) ? 1.f : 0.f;
    return ((const int*)m)[i] ? 1.f : 0.f;
}

__device__ __forceinline__ float block_sum(float v, float* red) {
    int t = threadIdx.x;
    red[t] = v; __syncthreads();
    for (int s = 128; s > 0; s >>= 1) {
        if (t < s) red[t] += red[t + s];
        __syncthreads();
    }
    float r = red[0]; __syncthreads();
    return r;
}

// ---------------------------------------------------------------------------
// k_h: trunk, 4 rows/block, 512 threads, grid=128. Also zeroes the partial
// accumulators (node_delta, out2) and sniffs the mask dtype (block 0).
// ---------------------------------------------------------------------------
__global__ __launch_bounds__(512) void k_h(
    const float* __restrict__ feat,
    const float* __restrict__ Wc1, const float* __restrict__ bc1,
    const float* __restrict__ Wc2, const float* __restrict__ bc2,
    const float* __restrict__ Wn1, const float* __restrict__ bn1,
    const float* __restrict__ We1, const float* __restrict__ be1,
    const float* __restrict__ Wg,  const float* __restrict__ bg,
    const float* __restrict__ margin, const float* __restrict__ brisk,
    const unsigned int* __restrict__ amask_words,
    float* __restrict__ base_n, float* __restrict__ base_e,
    float* __restrict__ out_gate, int* __restrict__ flag,
    float* __restrict__ node_delta, float* __restrict__ out2)
{
    __shared__ __align__(16) float sF[4][256];
    __shared__ __align__(16) float sH[4][256];
    __shared__ float red[512];
    __shared__ int cls0, cls1;

    int t = threadIdx.x;
    int w = t >> 8;
    int c = t & 255;
    int b0 = blockIdx.x * 4;
    int r0 = 2 * w, r1 = 2 * w + 1;

    // zero partial accumulators (128 blocks x 512 thr)
    {
        int idx = blockIdx.x * 512 + t;
        node_delta[idx] = 0.f;                    // B*N = 131072: 2/thread
        node_delta[idx + 65536] = 0.f;
        float4 z4 = make_float4(0.f, 0.f, 0.f, 0.f);
        ((float4*)out2)[idx] = z4;                // B*E = 131072 f4: 2/thread
        ((float4*)out2)[idx + 65536] = z4;
    }

    if (blockIdx.x == 0) {
        if (t == 0) { cls0 = 0; cls1 = 0; }
        __syncthreads();
        if (t < 256) {
            unsigned int wd = amask_words[t];
            if (wd != 0u && wd != 1u) {
                if (wd == 0x3f800000u) atomicOr(&cls1, 1);
                else                   atomicOr(&cls0, 1);
            }
        }
        __syncthreads();
        if (t == 0) *flag = cls0 ? 1 : (cls1 ? 2 : 0);
    }

    sF[r0][c] = feat[(long)(b0 + r0) * D + c];
    sF[r1][c] = feat[(long)(b0 + r1) * D + c];
    __syncthreads();

    // ---- P1 ----
    {
        float aA[2] = {bc1[c], 0.f}, aB[2] = {bc1[c], 0.f};
        const float* Wp = Wc1 + c;
        for (int d0 = 0; d0 < D; d0 += 16) {
            float wv[16];
            #pragma unroll
            for (int k = 0; k < 16; k++) wv[k] = Wp[(long)(d0 + k) * H];
            #pragma unroll
            for (int k = 0; k < 16; k++) {
                aA[k & 1] = fmaf(sF[r0][d0 + k], wv[k], aA[k & 1]);
                aB[k & 1] = fmaf(sF[r1][d0 + k], wv[k], aB[k & 1]);
            }
        }
        sH[r0][c] = fmaxf(aA[0] + aA[1], 0.f);
        sH[r1][c] = fmaxf(aB[0] + aB[1], 0.f);
    }
    __syncthreads();

    // ---- P2 ----
    {
        float aA[2] = {bc2[c], 0.f}, aB[2] = {bc2[c], 0.f};
        const float* Wp = Wc2 + c;
        for (int d0 = 0; d0 < H; d0 += 16) {
            float wv[16];
            #pragma unroll
            for (int k = 0; k < 16; k++) wv[k] = Wp[(long)(d0 + k) * H];
            #pragma unroll
            for (int k = 0; k < 16; k++) {
                aA[k & 1] = fmaf(sH[r0][d0 + k], wv[k], aA[k & 1]);
                aB[k & 1] = fmaf(sH[r1][d0 + k], wv[k], aB[k & 1]);
            }
        }
        float hA = fmaxf(aA[0] + aA[1], 0.f);
        float hB = fmaxf(aB[0] + aB[1], 0.f);
        __syncthreads();
        sF[r0][c] = hA;
        sF[r1][c] = hB;
    }
    __syncthreads();

    // ---- gate per row ----
    #pragma unroll
    for (int rr = 0; rr < 2; rr++) {
        int r = 2 * w + rr;
        red[t] = sF[r][c] * Wg[c];
        __syncthreads();
        for (int s = 128; s > 0; s >>= 1) {
            if (c < s) red[t] += red[t + s];
            __syncthreads();
        }
        if (c == 0) {
            int b = b0 + r;
            float lg = 1.f / (1.f + expf(-(red[t] + bg[0])));
            out_gate[b] = ((margin[b] < 0.2f) || (brisk[b] > 0.6f) || (lg > 0.5f)) ? 1.f : 0.f;
        }
        __syncthreads();
    }

    // ---- P3: base_n / base_e ----
    {
        const float* W3  = w ? (We1 + c) : (Wn1 + c);
        float bias       = w ? be1[c]    : bn1[c];
        float* dst       = w ? base_e    : base_n;
        float aA[2] = {bias, 0.f}, aB[2] = {bias, 0.f};
        float aC[2] = {bias, 0.f}, aD[2] = {bias, 0.f};
        for (int d0 = 0; d0 < H; d0 += 16) {
            float wv[16];
            #pragma unroll
            for (int k = 0; k < 16; k++) wv[k] = W3[(long)(d0 + k) * H];
            #pragma unroll
            for (int k = 0; k < 16; k++) {
                aA[k & 1] = fmaf(sF[0][d0 + k], wv[k], aA[k & 1]);
                aB[k & 1] = fmaf(sF[1][d0 + k], wv[k], aB[k & 1]);
                aC[k & 1] = fmaf(sF[2][d0 + k], wv[k], aC[k & 1]);
                aD[k & 1] = fmaf(sF[3][d0 + k], wv[k], aD[k & 1]);
            }
        }
        dst[(long)(b0 + 0) * H + c] = aA[0] + aA[1];
        dst[(long)(b0 + 1) * H + c] = aB[0] + aB[1];
        dst[(long)(b0 + 2) * H + c] = aC[0] + aC[1];
        dst[(long)(b0 + 3) * H + c] = aD[0] + aD[1];
    }
}

// ---------------------------------------------------------------------------
// k_ne: j-split x2 for TLP. 256 threads = 4 waves; grid 1280 = 5120 waves
// (~5/SIMD) so LDS broadcast latency is finally hidden.
// Blocks [0,256): NODE — row-group rg=bid>>1 (4 rows, wave=row), j-half
//   jh=bid&1 (128 j). fp32 q=4. Partial sum -> atomicAdd(node_delta).
// Blocks [256,1280): EDGE — row b=(bid-256)>>1, j-half. f16 fdot2 q=4.
//   Partial sum -> atomicAdd(out2). Bias/gate/mask applied in k_fin.
// ---------------------------------------------------------------------------
__global__ __launch_bounds__(256, 2) void k_ne(
    const float* __restrict__ cs, const float* __restrict__ coords,
    const float* __restrict__ unc, const int* __restrict__ actions,
    const float* __restrict__ Wn1, const float* __restrict__ Wn2,
    const float* __restrict__ base_n,
    const float* __restrict__ es, const int* __restrict__ edges,
    const float* __restrict__ We1, const float* __restrict__ We2,
    const float* __restrict__ base_e,
    const float* __restrict__ gate,
    float* __restrict__ node_delta, float* __restrict__ out2)
{
    __shared__ __align__(16) float smem[4096];   // 16 KB
    int t = threadIdx.x;
    int w = t >> 6, lane = t & 63;

    if (blockIdx.x < 256) {
        // ================= NODE: 4 rows (wave=row), half j =================
        int rg = blockIdx.x >> 1;
        int jh = blockIdx.x & 1;
        int b0 = rg * 4;
        float* pack = smem;            // [128][12]
        float* sB   = smem + 1536;     // [4][128]

        if (t < 128) {
            float* p = pack + t * 12;
            int j = jh * 128 + t;
            #pragma unroll
            for (int k = 0; k < 10; k++) p[k] = Wn1[(long)(H + k) * H + j];
            p[10] = Wn2[j];
            p[11] = 0.f;
        }
        {
            int r = t >> 7, c0 = t & 127;
            sB[r * 128 + c0]       = base_n[(long)(b0 + r) * H + jh * 128 + c0];
            sB[(r + 2) * 128 + c0] = base_n[(long)(b0 + r + 2) * H + jh * 128 + c0];
        }
        __syncthreads();

        int b = b0 + w;
        float g = gate[b];
        if (g != 0.f) {
            float f8v[4], ug[4], acc[4];
            float f0[4], f1[4], f2[4], f3[4], f4[4], f5[4], f6[4], f7[4];
            #pragma unroll
            for (int q = 0; q < 4; q++) {
                int n = q * 64 + lane;
                const float4* cp = (const float4*)(coords + ((long)b * N + n) * C);
                float4 c0 = cp[0], c1 = cp[1];
                f0[q] = c0.x; f1[q] = c0.y; f2[q] = c0.z; f3[q] = c0.w;
                f4[q] = c1.x; f5[q] = c1.y; f6[q] = c1.z; f7[q] = c1.w;
                f8v[q] = cs[(long)b * N + n];
                int a = actions[(long)b * N + n];
                a = min(max(a, 0), U - 1);
                ug[q] = unc[(long)b * U + a];
                acc[q] = 0.f;
            }

            const float* sBw = sB + w * 128;
            #pragma unroll 4
            for (int j = 0; j < 128; j++) {
                const float* pj = pack + j * 12;
                float4 wa = *(const float4*)(pj);
                float4 wb = *(const float4*)(pj + 4);
                float4 wc = *(const float4*)(pj + 8);
                float bse = sBw[j];
                #pragma unroll
                for (int q = 0; q < 4; q++) {
                    float zA = fmaf(f0[q], wa.x, bse);
                    zA = fmaf(f1[q], wa.y, zA);
                    zA = fmaf(f2[q], wa.z, zA);
                    zA = fmaf(f3[q], wa.w, zA);
                    float zB = f4[q] * wb.x;
                    zB = fmaf(f5[q], wb.y, zB);
                    zB = fmaf(f6[q], wb.z, zB);
                    zB = fmaf(f7[q], wb.w, zB);
                    zB = fmaf(f8v[q], wc.x, zB);
                    zB = fmaf(ug[q], wc.y, zB);
                    acc[q] = fmaf(fmaxf(zA + zB, 0.f), wc.z, acc[q]);
                }
            }

            #pragma unroll
            for (int q = 0; q < 4; q++)
                atomicAdd(&node_delta[(long)b * N + q * 64 + lane], acc[q]);
        }
    } else {
        // ================= EDGE: 1 row, half j, f16 =================
        int eb = blockIdx.x - 256;
        int b = eb >> 1, jh = eb & 1;
        float g = gate[b];
        if (g == 0.f) return;          // partial stays 0; k_fin handles

        float*  A4 = smem;                     // [128] float4 (f16x2 x4)
        float2* B2 = (float2*)(smem + 512);    // [128] float2
        float*  sC = smem + 1024;              // [256][12]

        {
            const float4* g4 = (const float4*)(coords + (long)b * N * C);
            float4 c0 = g4[2 * t], c1 = g4[2 * t + 1];
            float4* d0 = (float4*)(sC + t * 12);
            d0[0] = c0; d0[1] = c1;
        }
        if (t < 128) {
            int j = jh * 128 + t;
            float w0 = We1[(long)(H + 0) * H + j];
            float w1 = We1[(long)(H + 1) * H + j];
            float w2 = We1[(long)(H + 2) * H + j];
            float w3 = We1[(long)(H + 3) * H + j];
            float w4 = We1[(long)(H + 4) * H + j];
            float w5 = We1[(long)(H + 5) * H + j];
            float w6 = We1[(long)(H + 6) * H + j];
            float w7 = We1[(long)(H + 7) * H + j];
            float w8 = We1[(long)(H + 8) * H + j];
            float w9 = We1[(long)(H + 9) * H + j];
            float we2 = We2[j];
            float bse = base_e[(long)b * H + j] + w9;   // emf==1 fold
            float4 av;
            av.x = bc_f(pkh(w0, w1)); av.y = bc_f(pkh(w2, w3));
            av.z = bc_f(pkh(w4, w5)); av.w = bc_f(pkh(w6, w7));
            ((float4*)A4)[t] = av;
            B2[t] = make_float2(bc_f(pkh(w8, we2)), bse);
        }
        __syncthreads();

        float p01[4], p23[4], p45[4], p67[4], pes[4], acc[4];
        #pragma unroll
        for (int q = 0; q < 4; q++) {
            int e = w * 256 + q * 64 + lane;
            long idx = (long)b * E + e;
            int2 ev = ((const int2*)edges)[idx];
            int s0 = min(max(ev.x, 0), N - 1);
            int d0 = min(max(ev.y, 0), N - 1);
            const float4* cs4 = (const float4*)(sC + s0 * 12);
            const float4* cd4 = (const float4*)(sC + d0 * 12);
            float4 sa = cs4[0], sb = cs4[1];
            float4 da = cd4[0], db = cd4[1];
            p01[q] = bc_f(pkh(da.x - sa.x, da.y - sa.y));
            p23[q] = bc_f(pkh(da.z - sa.z, da.w - sa.w));
            p45[q] = bc_f(pkh(db.x - sb.x, db.y - sb.y));
            p67[q] = bc_f(pkh(db.z - sb.z, db.w - sb.w));
            pes[q] = bc_f(pkh(es[idx], 0.f));
            acc[q] = 0.f;
        }

        const float4* A4v = (const float4*)A4;
        #pragma unroll 4
        for (int j = 0; j < 128; j++) {
            float4 av = A4v[j];
            float2 bv = B2[j];
            h2 w01 = bc_h(av.x), w23 = bc_h(av.y);
            h2 w45 = bc_h(av.z), w67 = bc_h(av.w);
            h2 w8x = bc_h(bv.x);
            float we2f = (float)(w8x.y);
            float bse = bv.y;
            #pragma unroll
            for (int q = 0; q < 4; q++) {
                float z = FDOT2(bc_h(p01[q]), w01, bse);
                z = FDOT2(bc_h(p23[q]), w23, z);
                z = FDOT2(bc_h(p45[q]), w45, z);
                z = FDOT2(bc_h(p67[q]), w67, z);
                z = FDOT2(bc_h(pes[q]), w8x, z);
                acc[q] = fmaf(fmaxf(z, 0.f), we2f, acc[q]);
            }
        }

        #pragma unroll
        for (int q = 0; q < 4; q++)
            atomicAdd(&out2[(long)b * E + w * 256 + q * 64 + lane], acc[q]);
    }
}

// ---------------------------------------------------------------------------
// k_fin: blocks [0,512) node rows — assemble raw from node_delta, center,
// top-2(+idx), margin, riskbase. Blocks [512,1024) edge rows — assemble
// refined_edge from partials, mean/var -> evar.
// ---------------------------------------------------------------------------
__global__ __launch_bounds__(256) void k_fin(
    const void* __restrict__ amask, const void* __restrict__ emask,
    const int* __restrict__ actions, const float* __restrict__ unc,
    const float* __restrict__ cs, const float* __restrict__ es,
    const float* __restrict__ bn2, const float* __restrict__ be2,
    const float* __restrict__ gate, const int* __restrict__ flagp,
    const float* __restrict__ node_delta,
    float* __restrict__ out0, float* __restrict__ out1,
    float* __restrict__ out2, float* __restrict__ out3,
    float* __restrict__ riskbase, float* __restrict__ evar)
{
    __shared__ float red[256];
    __shared__ int ridx[256];
    int t = threadIdx.x;
    int flag = *flagp;

    if (blockIdx.x < B) {
        // ---- node row ----
        int b = blockIdx.x;
        float g = gate[b];
        float am = mask_val(amask, (long)b * N + t, flag);
        float csv = cs[(long)b * N + t];
        int a = actions[(long)b * N + t];
        a = min(max(a, 0), U - 1);
        float ug = unc[(long)b * U + a];
        float nd = (node_delta[(long)b * N + t] + bn2[0]) * am;
        float raw = (csv + g * 0.1f * nd) * am;

        float sum = block_sum(raw, red);
        float cnt = block_sum(am, red);
        float denom = fmaxf(cnt, 1.f);
        float rs = (raw - sum / denom) * am;
        out0[(long)b * N + t] = rs;

        float masked = (am != 0.f) ? rs : -1e9f;

        red[t] = masked; ridx[t] = t; __syncthreads();
        for (int s = 128; s > 0; s >>= 1) {
            if (t < s) {
                float o = red[t + s]; int oi = ridx[t + s];
                if (o > red[t] || (o == red[t] && oi < ridx[t])) { red[t] = o; ridx[t] = oi; }
            }
            __syncthreads();
        }
        float v1 = red[0]; int i1 = ridx[0]; __syncthreads();

        red[t] = (t == i1) ? -1e9f : masked; __syncthreads();
        for (int s = 128; s > 0; s >>= 1) {
            if (t < s) red[t] = fmaxf(red[t], red[t + s]);
            __syncthreads();
        }
        float v2 = red[0]; __syncthreads();
        float rmargin = v1 - v2;

        float su = block_sum(ug * am, red);

        if (t == 0) {
            out1[b] = rmargin;
            out3[b] = (float)i1;
            float sig = 1.f / (1.f + expf(rmargin));   // sigmoid(-margin)
            riskbase[b] = sig + 0.1f * (su / denom);
        }
    } else {
        // ---- edge row ----
        int b = blockIdx.x - B;
        float g = gate[b];
        float be2v = be2[0];

        float re[4], emv[4];
        #pragma unroll
        for (int q = 0; q < 4; q++) {
            long idx = (long)b * E + t + 256 * q;
            emv[q] = mask_val(emask, idx, flag);
            float delta = out2[idx] + be2v;
            float r = es[idx] + g * 0.1f * delta;
            re[q] = (emv[q] != 0.f) ? r : 0.f;
            out2[idx] = re[q];
        }

        float S1 = 0.f, ce = 0.f;
        #pragma unroll
        for (int q = 0; q < 4; q++) { S1 += re[q]; ce += emv[q]; }
        float S1t = block_sum(S1, red);
        float cet = block_sum(ce, red);
        float mean = S1t / fmaxf(cet, 1.f);
        float v = 0.f;
        #pragma unroll
        for (int q = 0; q < 4; q++) {
            float dd = re[q] - mean;
            v = fmaf(emv[q] * dd, dd, v);
        }
        float vt = block_sum(v, red);
        if (t == 0) {
            float var = vt / fmaxf(cet, 1.f);
            evar[b] = (cet > 1.f) ? var : 0.f;
        }
    }
}

// ---------------------------------------------------------------------------
__global__ __launch_bounds__(256) void k_risk(
    const float* __restrict__ riskbase, const float* __restrict__ evar,
    float* __restrict__ out4)
{
    int b = blockIdx.x * 256 + threadIdx.x;
    float r = riskbase[b] + 0.2f * evar[b];
    out4[b] = fminf(fmaxf(r, 0.f), 1.f);
}

// ---------------------------------------------------------------------------
extern "C" void kernel_launch(void* const* d_in, const int* in_sizes, int n_in,
                              void* d_out, int out_size, void* d_ws, size_t ws_size,
                              hipStream_t stream) {
    const float* feat   = (const float*)d_in[0];
    const float* cs     = (const float*)d_in[1];
    const float* marg   = (const float*)d_in[2];
    const float* brisk  = (const float*)d_in[3];
    const float* es     = (const float*)d_in[4];
    const float* coords = (const float*)d_in[5];
    const float* unc    = (const float*)d_in[6];
    const float* Wc1    = (const float*)d_in[7];
    const float* bc1    = (const float*)d_in[8];
    const float* Wc2    = (const float*)d_in[9];
    const float* bc2    = (const float*)d_in[10];
    const float* Wn1    = (const float*)d_in[11];
    const float* bn1    = (const float*)d_in[12];
    const float* Wn2    = (const float*)d_in[13];
    const float* bn2    = (const float*)d_in[14];
    const float* We1    = (const float*)d_in[15];
    const float* be1    = (const float*)d_in[16];
    const float* We2    = (const float*)d_in[17];
    const float* be2    = (const float*)d_in[18];
    const float* Wg     = (const float*)d_in[19];
    const float* bg     = (const float*)d_in[20];
    const void*  amask  = d_in[21];
    const void*  emask  = d_in[22];
    const int*   actions= (const int*)d_in[23];
    const int*   edges  = (const int*)d_in[24];

    float* out0 = (float*)d_out;           // refined_scores (B,N)
    float* out1 = out0 + (long)B * N;      // refined_margin (B,)
    float* out2 = out1 + B;                // refined_edge (B,E)
    float* out3 = out2 + (long)B * E;      // top_idx (B,) as float
    float* out4 = out3 + B;                // refined_risk (B,)
    float* out5 = out4 + B;                // refine_gate (B,)

    float* base_n     = (float*)d_ws;                  // B*H
    float* base_e     = base_n + (long)B * H;          // B*H
    float* node_delta = base_e + (long)B * H;          // B*N
    float* riskbase   = node_delta + (long)B * N;      // B
    float* evar       = riskbase + B;                  // B
    int*   flag       = (int*)(evar + B);

    k_h<<<B / 4, 512, 0, stream>>>(feat, Wc1, bc1, Wc2, bc2, Wn1, bn1, We1, be1,
                                   Wg, bg, marg, brisk,
                                   (const unsigned int*)amask,
                                   base_n, base_e, out5, flag,
                                   node_delta, out2);
    k_ne<<<256 + 2 * B, 256, 0, stream>>>(cs, coords, unc, actions,
                                          Wn1, Wn2, base_n,
                                          es, edges,
                                          We1, We2, base_e,
                                          out5, node_delta, out2);
    k_fin<<<2 * B, 256, 0, stream>>>(amask, emask, actions, unc, cs, es,
                                     bn2, be2, out5, flag, node_delta,
                                     out0, out1, out2, out3, riskbase, evar);
    k_risk<<<2, 256, 0, stream>>>(riskbase, evar, out4);
}